// Round 2
// baseline (631.896 us; speedup 1.0000x reference)
//
#include <hip/hip_runtime.h>

// BiLSTM: B=256, T=512, N=128, H=128. fp32 in/out, bf16 MFMA internally.
//
// Producer/consumer wave split, 128 blocks = 2 dirs x 64 batch-blocks of
// 4 rows (mapped to MFMA tile rows {0,4,8,12}; rows r%4!=0 are zero padding).
// 8 waves/block:
//   waves 0-3 ("X"): zx(s+1) = x(t(s+1))@W + b for gate wv (K=128, off the
//                    recurrent critical path), written to LDS fp32 tile.
//   waves 4-7 ("H"): z = zx(s) + h(s)@U (K=128 only -> 4 masked ds_read_b128
//                    + 4-deep MFMA chains), activations, h(s+1), out.
// A-reads exec-masked to the 16 real-row lanes (m%4==0); LDS strides chosen
// so masked reads are <=2-way bank-aliased (free). One barrier per step.
//
// ws layout (unchanged):
//   [0, 512KB): combined WU bf16 MFMA B-fragments
//               [dir(2)][gate(4)][kc(8)][tile(8)][lane(64)][8]
//               kc<4 -> W rows kc*32.., kc>=4 -> U rows (kc-4)*32..

typedef short s16x8 __attribute__((ext_vector_type(8)));
typedef float f32x4 __attribute__((ext_vector_type(4)));

#define NT 512

// Barrier with LDS-only drain: out-stores and the x prefetch stay in flight.
#define LDS_BARRIER() asm volatile("s_waitcnt lgkmcnt(0)\n\ts_barrier" ::: "memory")

__device__ __forceinline__ unsigned short f2bf(float f) {
  unsigned int u = __float_as_uint(f);
  u += 0x7fffu + ((u >> 16) & 1u);   // RNE
  return (unsigned short)(u >> 16);
}
__device__ __forceinline__ float sigm(float x) {
  return __builtin_amdgcn_rcpf(1.f + __expf(-x));
}
__device__ __forceinline__ float tanh_(float x) {
  float xc = fminf(fmaxf(x, -12.f), 12.f);
  return 1.f - 2.f * __builtin_amdgcn_rcpf(1.f + __expf(2.f * xc));
}

// ---------------------------------------------------------------- kernel 0
// Repack [W;U] (fp32 [128][512] each) into bf16 B-fragment order, K=256.
// B-frag (16x16x32): lane holds B[k = (lane>>4)*8 + j][n = lane&15].
__global__ void prep_frags(const float* __restrict__ Wf, const float* __restrict__ Uf,
                           const float* __restrict__ Wb, const float* __restrict__ Ub,
                           unsigned short* __restrict__ frag) {
  int idx = blockIdx.x * 256 + threadIdx.x;          // 0 .. 2^18-1
  int j    = idx & 7;
  int lane = (idx >> 3) & 63;
  int tile = (idx >> 9) & 7;
  int kc   = (idx >> 12) & 7;
  int gate = (idx >> 15) & 3;
  int dir  = (idx >> 17) & 1;
  const float* M = (kc < 4) ? (dir ? Wb : Wf) : (dir ? Ub : Uf);
  int k   = (kc & 3) * 32 + (lane >> 4) * 8 + j;
  int col = gate * 128 + tile * 16 + (lane & 15);
  frag[idx] = f2bf(M[k * 512 + col]);
}

// ---------------------------------------------------------------- kernel 1
__global__ __launch_bounds__(512, 2) void bilstm_rec(
    const unsigned short* __restrict__ frag, const float* __restrict__ x,
    const float* __restrict__ bfw, const float* __restrict__ bbw,
    float* __restrict__ out) {
  // h(s) bf16, rows 16 (12 zero rows), stride 132 bf16 (66 dw): masked row
  // set {0,4,8,12} -> 264*4 = 8 mod 32 dw -> 2-way (free); 16B-aligned.
  __shared__ unsigned short hbuf[2][16][132];
  // x(t) bf16, 4 real rows only, stride 144 bf16 (72 dw = 8 mod 32, 16B-align).
  __shared__ unsigned short xstage[2][4][144];
  // zx fp32 [4 rows][512 cols], stride 520 (8 mod 32 dw).
  __shared__ float zxbuf[2][4][520];

  int bid = blockIdx.x;
  int bblk = bid & 63, dir = bid >> 6;
  int tid = threadIdx.x;
  int wv = tid >> 6, lane = tid & 63, quad = lane >> 4, m = lane & 15;
  bool isx = (wv < 4);
  int w4 = wv & 3;
  bool mrow = ((m & 3) == 0);   // lane holds a real A-row
  int mu = m >> 2;

  // Weight fragments: 32 frags -> 128 VGPRs.
  // X wave wv: W-frags, gate wv, kc 0..3, tiles 0..7.
  // H wave wv: U-frags, kc 0..3 (U rows), tile (h2*4+w4) of each gate g.
  s16x8 wu[32];
  if (isx) {
#pragma unroll
    for (int kc = 0; kc < 4; kc++)
#pragma unroll
      for (int t = 0; t < 8; t++)
        wu[kc * 8 + t] = *(const s16x8*)(frag +
            ((((size_t)(dir * 4 + w4) * 8 + kc) * 8 + t) * 64 + lane) * 8);
  } else {
#pragma unroll
    for (int kc = 0; kc < 4; kc++)
#pragma unroll
      for (int g = 0; g < 4; g++)
#pragma unroll
        for (int h2 = 0; h2 < 2; h2++)
          wu[kc * 8 + g * 2 + h2] = *(const s16x8*)(frag +
              ((((size_t)(dir * 4 + g) * 8 + 4 + kc) * 8 + (h2 * 4 + w4)) * 64 + lane) * 8);
  }

  // Bias: folded into zx by X waves (acc init). H waves init 0.
  float bv[8];
  {
    const float* bias = dir ? bbw : bfw;
#pragma unroll
    for (int t = 0; t < 8; t++)
      bv[t] = isx ? bias[w4 * 128 + t * 16 + m] : 0.f;
  }

  // x staging: thread -> (srow 0..3, scol 0..127), coalesced loads.
  int srow = tid >> 7, scol = tid & 127;
  const float* xsrc = x + ((size_t)(bblk * 4 + srow) * NT) * 128 + scol;

  // zero hbuf (both buffers: padding rows must stay 0 forever; h(0)=0)
  {
    unsigned int* zp = (unsigned int*)&hbuf[0][0][0];
    for (int i = tid; i < 2 * 16 * 66; i += 512) zp[i] = 0;
  }
  // prologue: stage x(t(0)) -> xstage[0]
  {
    int t0 = dir ? (NT - 1) : 0;
    xstage[0][srow][scol] = f2bf(xsrc[(size_t)t0 * 128]);
  }
  __syncthreads();

  s16x8 a[4];
#pragma unroll
  for (int kc = 0; kc < 4; kc++) a[kc] = (s16x8){0, 0, 0, 0, 0, 0, 0, 0};

  float cc0 = 0.f, cc1 = 0.f;
  float* outp = out + ((size_t)(bblk * 4 + quad) * NT) * 256 + dir * 128 + w4 * 16 + m;

  for (int s = -1; s < NT; s++) {
    int cb = s & 1, nb = cb ^ 1;          // s=-1 -> cb=1 (zeroed hbuf, unused zx)
    bool hact = (!isx) && (s >= 0);

    // x prefetch for t(s+2): issued at top, consumed (f2bf+LDS) at bottom.
    int sn = s + 2; if (sn > NT - 1) sn = NT - 1;
    int tn = dir ? (NT - 1 - sn) : sn;
    float vx = xsrc[(size_t)tn * 128];

    // A-frags, exec-masked to the 16 real-row lanes. Inactive lanes keep 0.
    if (isx) {
      if (mrow) {
#pragma unroll
        for (int kc = 0; kc < 4; kc++)
          a[kc] = *(const s16x8*)(&xstage[nb][mu][kc * 32 + quad * 8]);
      }
    } else {
      if (mrow) {
#pragma unroll
        for (int kc = 0; kc < 4; kc++)
          a[kc] = *(const s16x8*)(&hbuf[cb][m][kc * 32 + quad * 8]);
      }
    }

    // zx gather for H (off MFMA critical path; added after accumulation)
    float zxv[8] = {};
    if (hact) {
#pragma unroll
      for (int g = 0; g < 4; g++)
#pragma unroll
        for (int h2 = 0; h2 < 2; h2++)
          zxv[g * 2 + h2] = zxbuf[cb][quad][g * 128 + h2 * 64 + w4 * 16 + m];
    }

    f32x4 acc[8];
#pragma unroll
    for (int t = 0; t < 8; t++) {
      acc[t][0] = bv[t]; acc[t][1] = bv[t]; acc[t][2] = bv[t]; acc[t][3] = bv[t];
    }
#pragma unroll
    for (int kc = 0; kc < 4; kc++)
#pragma unroll
      for (int t = 0; t < 8; t++)
        acc[t] = __builtin_amdgcn_mfma_f32_16x16x32_bf16(a[kc], wu[kc * 8 + t], acc[t], 0, 0, 0);

    if (isx) {
      // write zx(s+1): every lane's acc[t][0] is real (row quad*4 = batch row quad)
#pragma unroll
      for (int t = 0; t < 8; t++)
        zxbuf[nb][quad][w4 * 128 + t * 16 + m] = acc[t][0];
    } else if (hact) {
#pragma unroll
      for (int h2 = 0; h2 < 2; h2++) {
        float zi = acc[0 + h2][0] + zxv[0 + h2];
        float zf = acc[2 + h2][0] + zxv[2 + h2];
        float zg = acc[4 + h2][0] + zxv[4 + h2];
        float zo = acc[6 + h2][0] + zxv[6 + h2];
        float iv = sigm(zi);
        float fv = sigm(zf);
        float gv = tanh_(zg);
        float ov = sigm(zo);
        float& ccr = h2 ? cc1 : cc0;
        ccr = fv * ccr + iv * gv;
        float hv = ov * tanh_(ccr);
        hbuf[nb][quad * 4][h2 * 64 + w4 * 16 + m] = f2bf(hv);
        outp[(size_t)s * 256 + h2 * 64] = hv;   // in-flight across barrier
      }
    }

    // stage x(t(s+2)) into xstage[cb] (read next step as nb)
    xstage[cb][srow][scol] = f2bf(vx);

    LDS_BARRIER();
  }
}

extern "C" void kernel_launch(void* const* d_in, const int* in_sizes, int n_in,
                              void* d_out, int out_size, void* d_ws, size_t ws_size,
                              hipStream_t stream) {
  const float* x  = (const float*)d_in[0];
  const float* Wf = (const float*)d_in[1];
  const float* Uf = (const float*)d_in[2];
  const float* bf = (const float*)d_in[3];
  const float* Wb = (const float*)d_in[4];
  const float* Ub = (const float*)d_in[5];
  const float* bb = (const float*)d_in[6];
  float* out = (float*)d_out;

  unsigned short* frag = (unsigned short*)d_ws;

  prep_frags<<<1024, 256, 0, stream>>>(Wf, Uf, Wb, Ub, frag);
  bilstm_rec<<<128, 512, 0, stream>>>(frag, x, bf, bb, out);
}

// Round 3
// 492.693 us; speedup vs baseline: 1.2825x; 1.2825x over previous
//
#include <hip/hip_runtime.h>

// BiLSTM: B=256, T=512, N=128, H=128. fp32 in/out, bf16 MFMA internally.
//
// 128 blocks = 2 dirs x 64 batch-blocks of 4 rows, rows mapped to MFMA tile
// rows {0,4,8,12} (rows r%4!=0 are permanent zero padding; MFMA C-row r
// depends only on A-row r so padding never contaminates real rows).
// 8 uniform waves; wave = column-slice tc (16 cols x all 4 gates) so i,f,g,o
// stay in-register. One LDS barrier per step.
//
// Round-3 changes vs the 479us round-1 version:
//   * 2-step-deep x prefetch (two rotating register slots, unroll-by-2):
//     the global x load was only 1 body (~500cy) ahead of its vmcnt wait but
//     misses L3 (~900cy) -> every step stalled before the barrier. Now loads
//     are issued 2 barriers ahead.
//   * exec-masked A-fragment reads (only the 16 real-row lanes issue
//     ds_read_b128), LDS row stride 264 bf16 = 132 dw: 16B-aligned rows and
//     used-row set {0,4,8,12} -> dw offsets {0,16,0,16} mod 32 = 2-way (free).
//
// ws layout:
//   [0, 512KB): combined WU bf16 MFMA B-fragments
//               [dir(2)][gate(4)][kc(8)][tile(8)][lane(64)][8]
//               kc<4 -> W rows kc*32.., kc>=4 -> U rows (kc-4)*32..

typedef short s16x8 __attribute__((ext_vector_type(8)));
typedef float f32x4 __attribute__((ext_vector_type(4)));

#define NT 512
#define LDSROW 264   // bf16 per row: 256 data + 8 pad. 132 dw, 16B-aligned.

// Barrier with LDS-only drain: out-stores and x prefetches stay in flight.
#define LDS_BARRIER() asm volatile("s_waitcnt lgkmcnt(0)\n\ts_barrier" ::: "memory")

__device__ __forceinline__ unsigned short f2bf(float f) {
  unsigned int u = __float_as_uint(f);
  u += 0x7fffu + ((u >> 16) & 1u);   // RNE
  return (unsigned short)(u >> 16);
}
__device__ __forceinline__ float sigm(float x) {
  return __builtin_amdgcn_rcpf(1.f + __expf(-x));
}
__device__ __forceinline__ float tanh_(float x) {
  float xc = fminf(fmaxf(x, -12.f), 12.f);
  return 1.f - 2.f * __builtin_amdgcn_rcpf(1.f + __expf(2.f * xc));
}

// ---------------------------------------------------------------- kernel 0
// Repack [W;U] (fp32 [128][512] each) into bf16 B-fragment order, K=256.
// B-frag (16x16x32): lane holds B[k = (lane>>4)*8 + j][n = lane&15].
__global__ void prep_frags(const float* __restrict__ Wf, const float* __restrict__ Uf,
                           const float* __restrict__ Wb, const float* __restrict__ Ub,
                           unsigned short* __restrict__ frag) {
  int idx = blockIdx.x * 256 + threadIdx.x;          // 0 .. 2^18-1
  int j    = idx & 7;
  int lane = (idx >> 3) & 63;
  int tile = (idx >> 9) & 7;
  int kc   = (idx >> 12) & 7;
  int gate = (idx >> 15) & 3;
  int dir  = (idx >> 17) & 1;
  const float* M = (kc < 4) ? (dir ? Wb : Wf) : (dir ? Ub : Uf);
  int k   = (kc & 3) * 32 + (lane >> 4) * 8 + j;
  int col = gate * 128 + tile * 16 + (lane & 15);
  frag[idx] = f2bf(M[k * 512 + col]);
}

// ---------------------------------------------------------------- kernel 1
__global__ __launch_bounds__(512, 2) void bilstm_rec(
    const unsigned short* __restrict__ frag, const float* __restrict__ x,
    const float* __restrict__ bfw, const float* __restrict__ bbw,
    float* __restrict__ out) {
  __shared__ unsigned short xh[2][16][LDSROW];   // cols 0..127 = x_t, 128..255 = h

  int bid = blockIdx.x;
  int bblk = bid & 63, dir = bid >> 6;
  int tid = threadIdx.x;
  int tc = tid >> 6, lane = tid & 63, quad = lane >> 4, m = lane & 15;
  bool mrow = ((m & 3) == 0);   // lane holds a real A-row (tile row m in {0,4,8,12})

  // WU fragments for (dir, all gates, tile tc): 32 frags -> 128 VGPRs
  s16x8 wu[4][8];   // [gate][kc]
#pragma unroll
  for (int g = 0; g < 4; g++)
#pragma unroll
    for (int kc = 0; kc < 8; kc++)
      wu[g][kc] = *(const s16x8*)(frag +
          ((((size_t)(dir * 4 + g) * 8 + kc) * 8 + tc) * 64 + lane) * 8);

  const float* bias = dir ? bbw : bfw;
  float bv[4];
#pragma unroll
  for (int g = 0; g < 4; g++) bv[g] = bias[g * 128 + tc * 16 + m];

  // x staging ownership: thread -> (real row srow 0..3, col scol 0..127)
  int srow = tid >> 7, scol = tid & 127;
  const float* xsrc = x + ((size_t)(bblk * 4 + srow) * NT) * 128 + scol;

  // zero ALL of LDS (padding rows must read 0 forever; h(0) = 0)
  {
    unsigned int* zp = (unsigned int*)&xh[0][0][0];
    for (int i = tid; i < 2 * 16 * (LDSROW / 2); i += 512) zp[i] = 0;
  }
  __syncthreads();

  // prologue: stage x(t(0)); prefetch t(1), t(2) into rotating slots
  {
    int t0 = dir ? (NT - 1) : 0;
    xh[0][srow * 4][scol] = f2bf(xsrc[(size_t)t0 * 128]);
  }
  float vxA = xsrc[(size_t)(dir ? (NT - 2) : 1) * 128];
  float vxB = xsrc[(size_t)(dir ? (NT - 3) : 2) * 128];
  __syncthreads();

  s16x8 a[8];
#pragma unroll
  for (int kc = 0; kc < 8; kc++) a[kc] = (s16x8){0, 0, 0, 0, 0, 0, 0, 0};

  float cc = 0.f;   // cell state: lane owns (batch row quad, col tc*16+m)
  float* outp = out + ((size_t)(bblk * 4 + quad) * NT) * 256 + dir * 128 + tc * 16 + m;

  auto body = [&](int s, float& vx) {
    int cb = s & 1, nb = cb ^ 1;

    // issue x load for step s+2's consumption (t(s+3)): ~2 bodies of cover
    int sn = s + 3; if (sn > NT - 1) sn = NT - 1;
    int tn = dir ? (NT - 1 - sn) : sn;
    float vnew = xsrc[(size_t)tn * 128];

    // A-frags [x_t | h], exec-masked to real-row lanes (2-way banks, free)
    if (mrow) {
#pragma unroll
      for (int kc = 0; kc < 8; kc++)
        a[kc] = *(const s16x8*)(&xh[cb][m][kc * 32 + quad * 8]);
    }

    f32x4 acc[4];
#pragma unroll
    for (int g = 0; g < 4; g++) {
      acc[g][0] = bv[g]; acc[g][1] = bv[g]; acc[g][2] = bv[g]; acc[g][3] = bv[g];
    }
#pragma unroll
    for (int kc = 0; kc < 8; kc++)
#pragma unroll
      for (int g = 0; g < 4; g++)
        acc[g] = __builtin_amdgcn_mfma_f32_16x16x32_bf16(a[kc], wu[g][kc], acc[g], 0, 0, 0);

    // activations on the single real element: C row quad*4 (reg 0)
    float iv = sigm(acc[0][0]);
    float fv = sigm(acc[1][0]);
    float gv = tanh_(acc[2][0]);
    float ov = sigm(acc[3][0]);
    cc = fv * cc + iv * gv;
    float hv = ov * tanh_(cc);

    // LDS writes (gate the barrier's lgkmcnt drain)
    xh[nb][quad * 4][128 + tc * 16 + m] = f2bf(hv);
    xh[nb][srow * 4][scol] = f2bf(vx);   // consume slot: x(t(s+1))

    // global out store last (stays in flight across the barrier)
    outp[(size_t)s * 256] = hv;

    LDS_BARRIER();
    vx = vnew;   // rotate slot (SSA: wait lands at the consume, 2 bodies later)
  };

  for (int s = 0; s < NT; s += 2) {
    body(s, vxA);
    body(s + 1, vxB);
  }
}

extern "C" void kernel_launch(void* const* d_in, const int* in_sizes, int n_in,
                              void* d_out, int out_size, void* d_ws, size_t ws_size,
                              hipStream_t stream) {
  const float* x  = (const float*)d_in[0];
  const float* Wf = (const float*)d_in[1];
  const float* Uf = (const float*)d_in[2];
  const float* bf = (const float*)d_in[3];
  const float* Wb = (const float*)d_in[4];
  const float* Ub = (const float*)d_in[5];
  const float* bb = (const float*)d_in[6];
  float* out = (float*)d_out;

  unsigned short* frag = (unsigned short*)d_ws;

  prep_frags<<<1024, 256, 0, stream>>>(Wf, Uf, Wb, Ub, frag);
  bilstm_rec<<<128, 512, 0, stream>>>(frag, x, bf, bb, out);
}